// Round 1
// baseline (132.644 us; speedup 1.0000x reference)
//
#include <hip/hip_runtime.h>
#include <hip/hip_bf16.h>

// VQ quantizer: ze [65536 x 128] f32, codebook [2048 x 128] f32.
// out[m,:] = codebook[argmin_k ||z_m - c_k||^2, :]
//
// Round 8: double-buffered B tile (64 KB LDS), ONE raw s_barrier per tile
// with counted vmcnt (stage issued right after the barrier, waited a full
// tile later -> in flight across MFMA+epilogue), setprio(1) around the
// MFMA cluster. Numerics identical to round 7.
//  vq_prepn:  codebook -> bf16 hi + lo residual; cn[k] = ||c_k||^2 (fp32).
//  vq_score:  3-term bf16 MFMA (hi*hi + lo*hi + hi*lo), per-row streaming
//             top-2; flags rows with margin < 0.02 (~0.9%).
//  vq_rescue: exact-fp32 rescan of flagged rows (R1 summation order),
//             packed (score,idx) atomicMin -> first-index, deterministic.
//  vq_fix:    outIdx[row] = low32(g_res[row]).
//  vq_gather: out = codebook[idx].

#define VQ_D 128
#define VQ_K 2048
#define VQ_M 65536
#define VQ_THR 0.02f

typedef short short8 __attribute__((ext_vector_type(8)));
typedef float f32x4 __attribute__((ext_vector_type(4)));
typedef float f32x16 __attribute__((ext_vector_type(16)));
typedef unsigned long long u64;

__device__ uint4 g_cbh[VQ_K * VQ_D / 8];   // codebook bf16 hi, 16 chunks/row
__device__ uint4 g_cbl[VQ_K * VQ_D / 8];   // codebook bf16 lo (residual)
__device__ int   g_list[VQ_M];
__device__ u64   g_res[VQ_M];
__device__ int   g_count;

__device__ __forceinline__ unsigned rne16(unsigned u) {
    return u + 0x7FFFu + ((u >> 16) & 1u);     // RNE to bf16 (finite inputs)
}
__device__ __forceinline__ void split2(float a, float b, unsigned& hi, unsigned& lo) {
    unsigned ra = rne16(__float_as_uint(a)) & 0xFFFF0000u;
    unsigned rb = rne16(__float_as_uint(b)) & 0xFFFF0000u;
    float la = a - __uint_as_float(ra);
    float lb = b - __uint_as_float(rb);
    hi = rb | (ra >> 16);
    lo = (rne16(__float_as_uint(lb)) & 0xFFFF0000u) | (rne16(__float_as_uint(la)) >> 16);
}

// prep + cnorm fused: thread g handles 8 elems of row g>>4 (16 threads/row)
__global__ void vq_prepn(const float* __restrict__ cb, float* __restrict__ cn) {
    int g = blockIdx.x * 256 + threadIdx.x;          // 0..32767
    const float4* s = reinterpret_cast<const float4*>(cb) + (size_t)g * 2;
    float4 f0 = s[0], f1 = s[1];
    uint4 h, l;
    split2(f0.x, f0.y, h.x, l.x);
    split2(f0.z, f0.w, h.y, l.y);
    split2(f1.x, f1.y, h.z, l.z);
    split2(f1.z, f1.w, h.w, l.w);
    g_cbh[g] = h;
    g_cbl[g] = l;
    float v = ((f0.x * f0.x + f0.y * f0.y) + (f0.z * f0.z + f0.w * f0.w))
            + ((f1.x * f1.x + f1.y * f1.y) + (f1.z * f1.z + f1.w * f1.w));
    v += __shfl_xor(v, 1);
    v += __shfl_xor(v, 2);
    v += __shfl_xor(v, 4);
    v += __shfl_xor(v, 8);
    if ((g & 15) == 0) cn[g >> 4] = v;
    if (g == 0) g_count = 0;
}

__global__ __launch_bounds__(256)
void vq_score(const float* __restrict__ ze,
              const float* __restrict__ cn,
              int* __restrict__ outIdx) {
    __shared__ uint4 sB[4096];   // 64 KB: prologue A staging (first 32 KB);
                                 // main loop: double-buffered B tile.
                                 // Per buffer (2048 slots): 64 codes,
                                 // hi slots 0..1023, lo 1024..2047.
    const int tid  = threadIdx.x;
    const int lane = tid & 63;
    const int wv   = tid >> 6;          // 0..3, wave owns 32 query rows
    const int ln31 = lane & 31;
    const int g2   = lane >> 5;         // 0/1: k-octet within K=16 step
    const int qb   = blockIdx.x * 128;

    // ---- prologue: split 128 query rows, A hi+lo -> registers via LDS ----
    uint4 hbuf[8], lbuf[8];
    #pragma unroll
    for (int jj = 0; jj < 8; ++jj) {
        int id = jj * 256 + tid, r = id >> 4, c = id & 15;
        const float4* src =
            reinterpret_cast<const float4*>(ze + (size_t)(qb + r) * VQ_D + c * 8);
        float4 f0 = src[0], f1 = src[1];
        uint4 h, l;
        split2(f0.x, f0.y, h.x, l.x);
        split2(f0.z, f0.w, h.y, l.y);
        split2(f1.x, f1.y, h.z, l.z);
        split2(f1.z, f1.w, h.w, l.w);
        hbuf[jj] = h; lbuf[jj] = l;
    }
    #pragma unroll
    for (int jj = 0; jj < 8; ++jj) {
        int id = jj * 256 + tid, r = id >> 4, c = id & 15;
        sB[r * 16 + (c ^ (r & 15))] = hbuf[jj];
    }
    __syncthreads();
    short8 ahi[8], alo[8];
    {
        int r = wv * 32 + ln31;
        #pragma unroll
        for (int kc = 0; kc < 8; ++kc)
            ahi[kc] = *(const short8*)&sB[r * 16 + ((kc * 2 + g2) ^ (r & 15))];
    }
    __syncthreads();
    #pragma unroll
    for (int jj = 0; jj < 8; ++jj) {
        int id = jj * 256 + tid, r = id >> 4, c = id & 15;
        sB[r * 16 + (c ^ (r & 15))] = lbuf[jj];
    }
    __syncthreads();
    {
        int r = wv * 32 + ln31;
        #pragma unroll
        for (int kc = 0; kc < 8; ++kc)
            alo[kc] = *(const short8*)&sB[r * 16 + ((kc * 2 + g2) ^ (r & 15))];
    }
    __syncthreads();

    // ---- stage B tile into buffer BUF (pre-swizzled global src, linear LDS dst)
    #define STAGE_B(T, BUF)                                                     \
        _Pragma("unroll")                                                       \
        for (int jj = 0; jj < 4; ++jj) {                                        \
            int base = wv * 256 + jj * 64;                                      \
            int p = base + lane, r = p >> 4, c = (p & 15) ^ (r & 15);           \
            size_t si = (size_t)((T) * 64 + r) * 16 + c;                        \
            __builtin_amdgcn_global_load_lds((const void*)(g_cbh + si),         \
                    (void*)(sB + (BUF) * 2048 + base), 16, 0, 0);               \
            __builtin_amdgcn_global_load_lds((const void*)(g_cbl + si),         \
                    (void*)(sB + (BUF) * 2048 + 1024 + base), 16, 0, 0);        \
        }
    STAGE_B(0, 0)

    float m1[16], m2[16];
    int   i1[16];
    #pragma unroll
    for (int j = 0; j < 16; ++j) { m1[j] = 3.0e38f; m2[j] = 3.0e38f; i1[j] = 0; }

    float cn0 = cn[ln31], cn1 = cn[32 + ln31];

    for (int tile = 0; tile < VQ_K / 64; ++tile) {
        // My stage-for-tile loads (and cn prefetch) were issued a full
        // iteration ago -> this drain is cheap. Each wave waits its OWN
        // loads, then the raw barrier makes the whole tile visible.
        asm volatile("s_waitcnt vmcnt(0)" ::: "memory");
        __builtin_amdgcn_s_barrier();
        __builtin_amdgcn_sched_barrier(0);   // nothing hoists above the barrier

        const int b2 = (tile & 1) << 11;     // current buffer base (uint4 slots)

        // Issue next tile's stage NOW: in flight across MFMA + epilogue.
        // Safe: buf[(tile+1)&1] was last read at iter tile-1, closed by the
        // barrier above.
        if (tile < VQ_K / 64 - 1) { STAGE_B(tile + 1, (tile + 1) & 1) }
        int nt = (tile < VQ_K / 64 - 1) ? tile + 1 : 0;
        float ncn0 = cn[nt * 64 + ln31];
        float ncn1 = cn[nt * 64 + 32 + ln31];

        f32x16 acc0, acc1;
        #pragma unroll
        for (int j = 0; j < 16; ++j) { acc0[j] = 0.f; acc1[j] = 0.f; }

        __builtin_amdgcn_s_setprio(1);
        #pragma unroll
        for (int kc = 0; kc < 8; ++kc) {
            int chs = (kc * 2 + g2) ^ (ln31 & 15);
            short8 bh0 = *(const short8*)&sB[b2 + ln31 * 16 + chs];
            short8 bl0 = *(const short8*)&sB[b2 + 1024 + ln31 * 16 + chs];
            short8 bh1 = *(const short8*)&sB[b2 + (32 + ln31) * 16 + chs];
            short8 bl1 = *(const short8*)&sB[b2 + 1024 + (32 + ln31) * 16 + chs];
            acc0 = __builtin_amdgcn_mfma_f32_32x32x16_bf16(ahi[kc], bh0, acc0, 0, 0, 0);
            acc0 = __builtin_amdgcn_mfma_f32_32x32x16_bf16(alo[kc], bh0, acc0, 0, 0, 0);
            acc0 = __builtin_amdgcn_mfma_f32_32x32x16_bf16(ahi[kc], bl0, acc0, 0, 0, 0);
            acc1 = __builtin_amdgcn_mfma_f32_32x32x16_bf16(ahi[kc], bh1, acc1, 0, 0, 0);
            acc1 = __builtin_amdgcn_mfma_f32_32x32x16_bf16(alo[kc], bh1, acc1, 0, 0, 0);
            acc1 = __builtin_amdgcn_mfma_f32_32x32x16_bf16(ahi[kc], bl1, acc1, 0, 0, 0);
        }
        __builtin_amdgcn_s_setprio(0);

        // ---- epilogue: scores for k = tile*64 + {ln31, 32+ln31}, 16 rows ----
        // No barrier here: next iteration's counted vmcnt + barrier both
        // close this tile's reads and open the next.
        int kb = tile * 64 + ln31;
        #pragma unroll
        for (int j = 0; j < 16; ++j) {
            float s0 = fmaf(-2.f, acc0[j], cn0);
            bool lt0 = s0 < m1[j];
            m2[j] = lt0 ? m1[j] : fminf(m2[j], s0);
            i1[j] = lt0 ? kb : i1[j];
            m1[j] = lt0 ? s0 : m1[j];
            float s1 = fmaf(-2.f, acc1[j], cn1);
            bool lt1 = s1 < m1[j];
            m2[j] = lt1 ? m1[j] : fminf(m2[j], s1);
            i1[j] = lt1 ? kb + 32 : i1[j];
            m1[j] = lt1 ? s1 : m1[j];
        }
        cn0 = ncn0; cn1 = ncn1;
    }

    // ---- cross-lane top-2 merge over the 32-lane code groups (g2 fixed) ----
    #pragma unroll
    for (int j = 0; j < 16; ++j) {
        float a1v = m1[j], a2v = m2[j];
        int   ai  = i1[j];
        #pragma unroll
        for (int off = 1; off < 32; off <<= 1) {
            float o1 = __shfl_xor(a1v, off);
            float o2 = __shfl_xor(a2v, off);
            int   oi = __shfl_xor(ai, off);
            bool lt = o1 < a1v;
            float hi = lt ? a1v : o1;
            a1v = lt ? o1 : a1v;
            ai  = lt ? oi : ai;
            a2v = fminf(fminf(a2v, o2), hi);
            // exact inter-lane tie -> a2v==a1v -> flagged -> rescued
        }
        if (ln31 == 0) {
            int row = qb + wv * 32 + (j & 3) + 8 * (j >> 2) + 4 * g2;
            outIdx[row] = ai;
            if (a2v - a1v < VQ_THR) {
                g_res[row] = ~0ull;
                int pos = atomicAdd(&g_count, 1);
                g_list[pos] = row;
            }
        }
    }
    #undef STAGE_B
}

__global__ __launch_bounds__(256)
void vq_rescue(const float* __restrict__ ze,
               const float* __restrict__ cb,
               const float* __restrict__ cn) {
    __shared__ float cs[64 * 132];    // 64 codes x 128, padded +4
    __shared__ float zs[4][128];      // 4 flagged rows

    const int tid  = threadIdx.x;
    const int lane = tid & 63;
    const int wv   = tid >> 6;          // 0..3: one flagged row per wave
    const int count = g_count;
    const long nitems = (long)((count + 3) >> 2) * 32;

    for (long it = blockIdx.x; it < nitems; it += gridDim.x) {
        const int grp   = (int)(it >> 5);
        const int chunk = (int)(it & 31);
        const int slot  = grp * 4 + wv;
        const bool valid = slot < count;
        const int row = g_list[valid ? slot : (count - 1)];

        #pragma unroll
        for (int j = 0; j < 8; ++j) {
            int id = j * 256 + tid;
            int r = id >> 5, col = id & 31;
            float4 v = reinterpret_cast<const float4*>(cb)[(size_t)(chunk * 64 + r) * 32 + col];
            *reinterpret_cast<float4*>(&cs[r * 132 + col * 4]) = v;
        }
        if (tid < 128) {
            int w = tid >> 5, i = tid & 31;
            int s2 = grp * 4 + w; if (s2 >= count) s2 = count - 1;
            int rw = g_list[s2];
            float4 v = reinterpret_cast<const float4*>(ze)[(size_t)rw * 32 + i];
            *reinterpret_cast<float4*>(&zs[w][i * 4]) = v;
        }
        __syncthreads();

        if (valid) {
            float4 zn = {0.f, 0.f, 0.f, 0.f};
            #pragma unroll
            for (int i = 0; i < 32; ++i) {
                float4 z = *reinterpret_cast<const float4*>(&zs[wv][i * 4]);
                zn.x += z.x * z.x; zn.y += z.y * z.y;
                zn.z += z.z * z.z; zn.w += z.w * z.w;
            }
            float znorm = (zn.x + zn.y) + (zn.z + zn.w);

            int k = chunk * 64 + lane;
            float4 a = {0.f, 0.f, 0.f, 0.f};
            #pragma unroll
            for (int i = 0; i < 32; ++i) {
                float4 c = *reinterpret_cast<const float4*>(&cs[lane * 132 + i * 4]);
                float4 z = *reinterpret_cast<const float4*>(&zs[wv][i * 4]);
                a.x += z.x * c.x; a.y += z.y * c.y;
                a.z += z.z * c.z; a.w += z.w * c.w;
            }
            float dot = (a.x + a.y) + (a.z + a.w);
            float s = fmaf(-2.f, dot, znorm + cn[k]);

            u64 p = ((u64)__float_as_uint(s) << 32) | (unsigned)k;
            #pragma unroll
            for (int o = 1; o < 64; o <<= 1) {
                u64 q = __shfl_xor(p, o);
                p = q < p ? q : p;
            }
            if (lane == 0) atomicMin(&g_res[row], p);
        }
        __syncthreads();
    }
}

__global__ void vq_fix(int* __restrict__ outIdx) {
    int n = g_count;
    for (int i = blockIdx.x * 256 + threadIdx.x; i < n; i += gridDim.x * 256) {
        int row = g_list[i];
        outIdx[row] = (int)(g_res[row] & 0xFFFFFFFFull);
    }
}

__global__ void vq_gather(const float* __restrict__ cb,
                          const int* __restrict__ idx,
                          float* __restrict__ out) {
    size_t u = (size_t)blockIdx.x * blockDim.x + threadIdx.x;
    int r = (int)(u >> 5);
    int j = (int)(u & 31);
    reinterpret_cast<float4*>(out)[u] =
        reinterpret_cast<const float4*>(cb)[((size_t)idx[r] << 5) + j];
}

extern "C" void kernel_launch(void* const* d_in, const int* in_sizes, int n_in,
                              void* d_out, int out_size, void* d_ws, size_t ws_size,
                              hipStream_t stream) {
    const float* ze = (const float*)d_in[0];
    const float* cb = (const float*)d_in[1];
    float* out = (float*)d_out;

    float* cn   = (float*)d_ws;                        // 2048 f32 = 8 KB
    int*   bidx = (int*)((char*)d_ws + 8192);          // 65536 i32 = 256 KB

    vq_prepn<<<VQ_K * VQ_D / 8 / 256, 256, 0, stream>>>(cb, cn);
    vq_score<<<VQ_M / 128, 256, 0, stream>>>(ze, cn, bidx);
    vq_rescue<<<1024, 256, 0, stream>>>(ze, cb, cn);
    vq_fix<<<64, 256, 0, stream>>>(bidx);
    vq_gather<<<(VQ_M * (VQ_D / 4)) / 256, 256, 0, stream>>>(cb, bidx, out);
}